// Round 1
// baseline (4912.053 us; speedup 1.0000x reference)
//
#include <hip/hip_runtime.h>

// ---------------------------------------------------------------------------
// ConversationLSTMStack: B=64, S=2048, D=H=768, L=2.
// Key identities (from the reference):
//   * h fed to every cell is zeros -> W_hh unused; gates = x @ W_ih^T + (b_ih+b_hh)
//   * per-layer gates are ONE big GEMM [B*S,768]x[768,3072]; recurrence is a pure
//     elementwise scan c = f*c + i*g (layer0: speaker-change resets c first).
// Plan: cast x -> bf16 (rows m = t*B+b), MFMA bf16 GEMM (m97-style 128x128 tile,
// global_load_lds width=16, XOR-swizzled LDS), fp32 gate buffer chunked in time
// (fits L3), fp32 scan kernel with depth-4 load pipeline.
// ---------------------------------------------------------------------------

typedef __attribute__((ext_vector_type(8))) short short8;
typedef __attribute__((ext_vector_type(4))) float floatx4;

#define B_ 64
#define S_ 2048
#define K_ 768
#define NG_ 3072  // 4*H

__device__ __forceinline__ unsigned short f2bf(float f) {
  unsigned int u = __builtin_bit_cast(unsigned int, f);
  u += 0x7fffu + ((u >> 16) & 1u);   // RTNE
  return (unsigned short)(u >> 16);
}

__device__ __forceinline__ float fsig(float x) {
  return __builtin_amdgcn_rcpf(1.f + __expf(-x));
}
__device__ __forceinline__ float mytanh(float x) {
  float e = __expf(-2.f * fabsf(x));
  float r = (1.f - e) * __builtin_amdgcn_rcpf(1.f + e);
  return __builtin_copysignf(r, x);
}

__device__ __forceinline__ void async16(const void* g, void* l) {
  __builtin_amdgcn_global_load_lds((__attribute__((address_space(1))) void*)g,
                                   (__attribute__((address_space(3))) void*)l,
                                   16, 0, 0);
}

// ---------------- prep kernels ----------------

__global__ __launch_bounds__(256) void prep_w(const float4* __restrict__ w4,
                                              ushort4* __restrict__ o4) {
  int idx = blockIdx.x * 256 + threadIdx.x;  // 2*3072*768/4 elems
  float4 v = w4[idx];
  ushort4 r;
  r.x = f2bf(v.x); r.y = f2bf(v.y); r.z = f2bf(v.z); r.w = f2bf(v.w);
  o4[idx] = r;
}

__global__ __launch_bounds__(256) void prep_small(const float* __restrict__ bih,
                                                  const float* __restrict__ bhh,
                                                  const int* __restrict__ parts,
                                                  float* __restrict__ bias,
                                                  int* __restrict__ rst) {
  int tid = blockIdx.x * 256 + threadIdx.x;  // 8192 threads
  if (tid < 2 * NG_) {
    bias[tid] = bih[tid] + bhh[tid];
  } else {
    int t = tid - 2 * NG_;
    rst[t] = (t == 0) ? 1 : ((parts[t] != parts[t - 1]) ? 1 : 0);
  }
}

// x [B,S,768] fp32 -> A0 bf16 rows m = t*B + b (K-contiguous)
__global__ __launch_bounds__(256) void cast_x(const float4* __restrict__ x4,
                                              ushort4* __restrict__ a4) {
  int idx = blockIdx.x * 256 + threadIdx.x;  // M*192
  int m = idx / 192;
  int j = idx - m * 192;
  int b = m & 63, t = m >> 6;
  float4 v = x4[(size_t)(b * S_ + t) * 192 + j];
  ushort4 r;
  r.x = f2bf(v.x); r.y = f2bf(v.y); r.z = f2bf(v.z); r.w = f2bf(v.w);
  a4[(size_t)m * 192 + j] = r;
}

// ---------------- GEMM: C[m,n] = sum_k A[m,k]*W[n,k] + bias[n] ----------------
// 128x128 block tile, BK=64, 4 waves (2x2 of 64x64), 16x16x32 bf16 MFMA.
// LDS tiles [128 rows][64 cols] bf16, 16B chunks XOR-swizzled by (row&7) so the
// 16-lane fragment reads (row stride 128B) are conflict-free.
__global__ __launch_bounds__(256) void gemm_bt(const unsigned short* __restrict__ A,
                                               const unsigned short* __restrict__ Bw,
                                               const float* __restrict__ bias,
                                               float* __restrict__ C) {
  __shared__ __align__(16) unsigned short At[128 * 64];
  __shared__ __align__(16) unsigned short Bt[128 * 64];
  const int tid = threadIdx.x;
  const int lane = tid & 63;
  const int wave = tid >> 6;
  const int wm = wave & 1, wn = wave >> 1;
  const int bm = blockIdx.x, bn = blockIdx.y;

  floatx4 acc[4][4] = {};

  const int rl = tid >> 3;  // 0..31
  const int cp = tid & 7;   // physical 16B chunk
  const size_t arow0 = (size_t)bm * 128;
  const size_t brow0 = (size_t)bn * 128;
  const int l15 = lane & 15, q = lane >> 4, sw = lane & 7;

  for (int kt = 0; kt < K_ / 64; ++kt) {
    const int k0 = kt * 64;
#pragma unroll
    for (int j = 0; j < 4; ++j) {
      int r = j * 32 + rl;
      int cl = cp ^ (r & 7);
      async16(A + (arow0 + r) * K_ + k0 + cl * 8, &At[r * 64 + cp * 8]);
      async16(Bw + (brow0 + r) * K_ + k0 + cl * 8, &Bt[r * 64 + cp * 8]);
    }
    __syncthreads();
#pragma unroll
    for (int ks = 0; ks < 2; ++ks) {
      short8 af[4], bf[4];
#pragma unroll
      for (int i = 0; i < 4; ++i) {
        int am = wm * 64 + i * 16 + l15;
        int bn_ = wn * 64 + i * 16 + l15;
        af[i] = *(const short8*)&At[am * 64 + ((ks * 4 + q) ^ sw) * 8];
        bf[i] = *(const short8*)&Bt[bn_ * 64 + ((ks * 4 + q) ^ sw) * 8];
      }
#pragma unroll
      for (int mi = 0; mi < 4; ++mi)
#pragma unroll
        for (int ni = 0; ni < 4; ++ni)
          acc[mi][ni] = __builtin_amdgcn_mfma_f32_16x16x32_bf16(
              af[mi], bf[ni], acc[mi][ni], 0, 0, 0);
    }
    __syncthreads();
  }

  // epilogue: D[row=q*4+r][col=lane&15]
#pragma unroll
  for (int ni = 0; ni < 4; ++ni) {
    int col = bn * 128 + wn * 64 + ni * 16 + l15;
    float bs = bias[col];
#pragma unroll
    for (int mi = 0; mi < 4; ++mi) {
      int row = bm * 128 + wm * 64 + mi * 16 + q * 4;
#pragma unroll
      for (int r = 0; r < 4; ++r)
        C[(size_t)(row + r) * NG_ + col] = acc[mi][ni][r] + bs;
    }
  }
}

// ---------------- scan: c = f*c + i*g over a time chunk ----------------
template <int LAYER>
__global__ __launch_bounds__(256) void scan_kernel(
    const float* __restrict__ G, int Tc, int t0, const int* __restrict__ rst,
    float* __restrict__ carry, unsigned short* __restrict__ h0out,
    float* __restrict__ out, float* __restrict__ hfin, float* __restrict__ cfin) {
  const int b = blockIdx.x / 3;
  const int h = (blockIdx.x % 3) * 256 + threadIdx.x;
  const int ci = b * K_ + h;
  float c = (t0 == 0) ? 0.f : carry[ci];

  float bi[4], bff[4], bg[4], bo[4];
#pragma unroll
  for (int d = 0; d < 4; ++d) {
    if (d < Tc) {
      size_t base = ((size_t)(d * B_ + b)) * NG_ + h;
      bi[d] = G[base];
      bff[d] = G[base + 768];
      bg[d] = G[base + 1536];
      bo[d] = G[base + 2304];
    }
  }
  for (int dt0 = 0; dt0 < Tc; dt0 += 4) {
#pragma unroll
    for (int u = 0; u < 4; ++u) {
      const int dt = dt0 + u;
      const int t = t0 + dt;
      float gi = bi[u], gf = bff[u], gg = bg[u], go = bo[u];
      int pre = dt + 4;
      if (pre < Tc) {
        size_t base = ((size_t)(pre * B_ + b)) * NG_ + h;
        bi[u] = G[base];
        bff[u] = G[base + 768];
        bg[u] = G[base + 1536];
        bo[u] = G[base + 2304];
      }
      if (LAYER == 0) {
        if (rst[t]) c = 0.f;
      }
      float iv = fsig(gi), fv = fsig(gf), gv = mytanh(gg), ov = fsig(go);
      c = fv * c + iv * gv;
      float hv = ov * mytanh(c);
      size_t orow = ((size_t)(t * B_ + b)) * K_ + h;
      if (LAYER == 0)
        h0out[orow] = f2bf(hv);
      else
        out[orow] = hv;
      if (t == S_ - 1) { hfin[ci] = hv; cfin[ci] = c; }
    }
  }
  carry[ci] = c;
}

// ---------------- host ----------------

extern "C" void kernel_launch(void* const* d_in, const int* in_sizes, int n_in,
                              void* d_out, int out_size, void* d_ws, size_t ws_size,
                              hipStream_t stream) {
  const float* x = (const float*)d_in[0];
  const float* Wih = (const float*)d_in[1];
  // d_in[2] = W_hh: provably unused (h0 == 0 always)
  const float* bih = (const float*)d_in[3];
  const float* bhh = (const float*)d_in[4];
  const int* parts = (const int*)d_in[5];

  char* ws = (char*)d_ws;
  // ws layout (bytes)
  unsigned short* A0h = (unsigned short*)(ws);               // 131072*768*2 = 201326592
  unsigned short* Wbf = (unsigned short*)(ws + 201326592);   // 2*3072*768*2 = 9437184
  float* bias = (float*)(ws + 210763776);                    // 2*3072*4     = 24576
  int* reset = (int*)(ws + 210788352);                       // 2048*4       = 8192
  float* carry = (float*)(ws + 210796544);                   // 2*49152*4    = 393216
  float* Gc = (float*)(ws + 211189760);                      // chunk*64*3072*4

  float* out0 = (float*)d_out;
  float* hfin = out0 + 100663296LL;  // S*B*H
  float* cfin = hfin + 98304;        // L*B*H

  // largest time-chunk whose fp32 gate buffer fits ws (256 preferred: 201MB ~ L3)
  int chunk = 4;
  const int cand[7] = {256, 128, 64, 32, 16, 8, 4};
  for (int i = 0; i < 7; ++i) {
    size_t need = 211189760ull + (size_t)cand[i] * B_ * NG_ * 4;
    if (need <= ws_size) { chunk = cand[i]; break; }
  }

  prep_w<<<4608, 256, 0, stream>>>((const float4*)Wih, (ushort4*)Wbf);
  prep_small<<<32, 256, 0, stream>>>(bih, bhh, parts, bias, reset);
  cast_x<<<98304, 256, 0, stream>>>((const float4*)x, (ushort4*)A0h);

  const int nch = S_ / chunk;
  for (int l = 0; l < 2; ++l) {
    const unsigned short* Wl = Wbf + (size_t)l * NG_ * K_;
    const float* bl = bias + l * NG_;
    float* cl = carry + l * 49152;
    for (int ci = 0; ci < nch; ++ci) {
      const unsigned short* Ac = A0h + (size_t)ci * chunk * B_ * K_;
      dim3 g(chunk * B_ / 128, NG_ / 128);
      gemm_bt<<<g, 256, 0, stream>>>(Ac, Wl, bl, Gc);
      if (l == 0)
        scan_kernel<0><<<192, 256, 0, stream>>>(Gc, chunk, ci * chunk, reset, cl,
                                                A0h, nullptr, hfin, cfin);
      else
        scan_kernel<1><<<192, 256, 0, stream>>>(Gc, chunk, ci * chunk, nullptr, cl,
                                                nullptr, out0, hfin + 49152,
                                                cfin + 49152);
    }
  }
}